// Round 13
// baseline (229.269 us; speedup 1.0000x reference)
//
#include <hip/hip_runtime.h>
#include <hip/hip_bf16.h>

// MHA: B=2, T=2048, DIM=1024, H=16, HD=64. fp32 in/out, bf16 internal.
// R13: attn = R10's proven per-wave body in SMALL INDEPENDENT blocks:
//   256 thr (4 waves x 16 q-rows = 64 rows/block), single-buffered K/V,
//   LDS 27.6 KB -> 4 resident blocks/CU = 16 waves in 4 independent
//   barrier groups (R8-R12 always had >=8-wave coupled groups, <=2/CU).
//   R12's zero-padded-PV formulation reverted (1.5x MFMA waste, regression).
// GEMM pipeline unchanged (R11): fused QKV + XCD swizzle + DMA dbuf.

using bf16x8 = __attribute__((ext_vector_type(8))) short;   // 8 bf16 in 4 VGPRs
using f32x4  = __attribute__((ext_vector_type(4))) float;   // MFMA accumulator

static __device__ __forceinline__ unsigned short f2bf(float f) {
    unsigned int u = __float_as_uint(f);
    unsigned int r = u + 0x7fffu + ((u >> 16) & 1u);   // RNE
    return (unsigned short)(r >> 16);
}

// async global->LDS DMA, 16 B/lane; lds dst wave-uniform (HW adds lane*16)
#define GLDS16(g, l) __builtin_amdgcn_global_load_lds(                    \
    (const __attribute__((address_space(1))) void*)(g),                   \
    (__attribute__((address_space(3))) void*)(l), 16, 0, 0)

// ---------------------------------------------------------------------------
// Fused conversions: id<2048 -> x fp32->bf16; id>=2048 -> W fp32 -> WT bf16.
// ---------------------------------------------------------------------------
__global__ __launch_bounds__(256) void conv(
    const float* __restrict__ x,
    const float* __restrict__ Wq, const float* __restrict__ Wk,
    const float* __restrict__ Wv, const float* __restrict__ Wo,
    ushort* __restrict__ xb, ushort* __restrict__ WT)
{
    int id = blockIdx.x;
    if (id < 2048) {
        int i8 = (id * 256 + threadIdx.x) * 8;
        float4 a = *reinterpret_cast<const float4*>(x + i8);
        float4 b = *reinterpret_cast<const float4*>(x + i8 + 4);
        ushort t[8] = {f2bf(a.x), f2bf(a.y), f2bf(a.z), f2bf(a.w),
                       f2bf(b.x), f2bf(b.y), f2bf(b.z), f2bf(b.w)};
        *reinterpret_cast<uint4*>(xb + i8) = *reinterpret_cast<const uint4*>(t);
    } else {
        int wid = id - 2048;
        int z   = wid >> 9;
        const float* src = (z == 0) ? Wq : (z == 1) ? Wk : (z == 2) ? Wv : Wo;
        ushort* dst = WT + (size_t)z * 1024 * 1024;
        int idx = (wid & 511) * 256 + threadIdx.x;
        int n   = idx & 1023;
        int k8  = (idx >> 10) << 3;
        ushort t[8];
#pragma unroll
        for (int e = 0; e < 8; e++) t[e] = f2bf(src[(size_t)(k8 + e) * 1024 + n]);
        *reinterpret_cast<uint4*>(dst + (size_t)n * 1024 + k8) =
            *reinterpret_cast<const uint4*>(t);
    }
}

// ---------------------------------------------------------------------------
// Fused QKV GEMM (unchanged R11) -> q (scaled 1/8), k, vT. XCD-swizzled.
// ---------------------------------------------------------------------------
#define CS 136

__global__ __launch_bounds__(256) void gemm_qkv(
    const ushort* __restrict__ Xb, const ushort* __restrict__ WT,
    const float* __restrict__ bq, const float* __restrict__ bk,
    const float* __restrict__ bv,
    ushort* __restrict__ q, ushort* __restrict__ k, ushort* __restrict__ v)
{
    __shared__ ushort smem[128 * CS];

    const int tid  = threadIdx.x;
    const int lane = tid & 63, wave = tid >> 6;
    const int l16  = lane & 15, quad = lane >> 4;
    const int wm   = (wave >> 1) * 64, wn = (wave & 1) * 64;
    const int flat = blockIdx.y * 24 + blockIdx.x;
    const int xcd  = flat & 7, lid = flat >> 3;
    const int mI   = xcd * 4 + (lid & 3);
    const int nI   = lid >> 2;
    const int m0   = mI * 128;
    const int n0g  = nI * 128;
    const int srow = lane >> 2, skoff = (lane & 3) * 8;

    f32x4 acc[4][4] = {};

#pragma unroll
    for (int c = 0; c < 2; c++) {
        int chunk = wave + c * 4;
        int row   = chunk * 16 + srow;
        GLDS16(Xb + (size_t)(m0 + row) * 1024 + skoff, smem + chunk * 512);
        GLDS16(WT + (size_t)(n0g + row) * 1024 + skoff, smem + 8192 + chunk * 512);
    }

    for (int i = 0; i < 32; i++) {
        const int p = i & 1;
        __syncthreads();
        if (i < 31) {
            int k0 = (i + 1) * 32;
#pragma unroll
            for (int c = 0; c < 2; c++) {
                int chunk = wave + c * 4;
                int row   = chunk * 16 + srow;
                GLDS16(Xb + (size_t)(m0 + row) * 1024 + k0 + skoff,
                       smem + (p ^ 1) * 4096 + chunk * 512);
                GLDS16(WT + (size_t)(n0g + row) * 1024 + k0 + skoff,
                       smem + 8192 + (p ^ 1) * 4096 + chunk * 512);
            }
        }
        const ushort* As = smem + p * 4096;
        const ushort* Bs = smem + 8192 + p * 4096;
        bf16x8 af[4], bfr[4];
#pragma unroll
        for (int t = 0; t < 4; t++) {
            af[t]  = *(const bf16x8*)&As[(wm + t * 16 + l16) * 32 + quad * 8];
            bfr[t] = *(const bf16x8*)&Bs[(wn + t * 16 + l16) * 32 + quad * 8];
        }
#pragma unroll
        for (int mt = 0; mt < 4; mt++)
#pragma unroll
            for (int nt = 0; nt < 4; nt++)
                acc[mt][nt] = __builtin_amdgcn_mfma_f32_16x16x32_bf16(
                    af[mt], bfr[nt], acc[mt][nt], 0, 0, 0);
    }

    const int mat = nI >> 3;
    const int nc0 = (nI & 7) * 128;
    const float* bias = (mat == 0) ? bq : (mat == 1) ? bk : bv;

    if (mat < 2) {
        ushort* Y = (mat == 0) ? q : k;
        const float scale = (mat == 0) ? 0.125f : 1.0f;   // 1/sqrt(64) into q
#pragma unroll
        for (int mt = 0; mt < 4; mt++) {
            int row = m0 + wm + mt * 16 + quad * 4;
#pragma unroll
            for (int nt = 0; nt < 4; nt++) {
                int col = nc0 + wn + nt * 16 + l16;
                float bvl = bias[col];
#pragma unroll
                for (int r = 0; r < 4; r++)
                    Y[(size_t)(row + r) * 1024 + col] = f2bf((acc[mt][nt][r] + bvl) * scale);
            }
        }
    } else {
        __syncthreads();
#pragma unroll
        for (int mt = 0; mt < 4; mt++) {
            int rowL = wm + mt * 16 + quad * 4;
#pragma unroll
            for (int nt = 0; nt < 4; nt++) {
                int colL = wn + nt * 16 + l16;
                float bvl = bias[nc0 + colL];
                ushort t4[4];
#pragma unroll
                for (int r = 0; r < 4; r++) t4[r] = f2bf(acc[mt][nt][r] + bvl);
                *(uint2*)&smem[colL * CS + rowL] = *(const uint2*)t4;
            }
        }
        __syncthreads();
        const int bb = m0 >> 11, tB = m0 & 2047;
#pragma unroll
        for (int it = 0; it < 8; it++) {
            int hdL = it * 16 + (tid >> 4);
            int tcL = (tid & 15) * 8;
            uint4 d = *(const uint4*)&smem[hdL * CS + tcL];
            int colG = nc0 + hdL;
            int hh = colG >> 6, hd = colG & 63;
            *(uint4*)&v[(size_t)((bb * 16 + hh) * 64 + hd) * 2048 + tB + tcL] = d;
        }
    }
}

// ---------------------------------------------------------------------------
// Out-proj GEMM (unchanged R11): ctx bf16 @ WTo -> out fp32. XCD-swizzled.
// ---------------------------------------------------------------------------
__global__ __launch_bounds__(256) void gemm_out(
    const ushort* __restrict__ Xb, const ushort* __restrict__ WT,
    const float* __restrict__ bias, float* __restrict__ Y)
{
    __shared__ ushort smem[12288];

    const int tid  = threadIdx.x;
    const int lane = tid & 63, wave = tid >> 6;
    const int l16  = lane & 15, quad = lane >> 4;
    const int wm   = (wave >> 1) * 64, wn = (wave & 1) * 32;
    const int flat = blockIdx.y * 16 + blockIdx.x;
    const int xcd  = flat & 7, lid = flat >> 3;
    const int m0   = (xcd * 4 + (lid & 3)) * 128;
    const int n0   = (lid >> 2) * 64;
    const int srow = lane >> 2, skoff = (lane & 3) * 8;

    f32x4 acc[4][2] = {};

#pragma unroll
    for (int c = 0; c < 2; c++) {
        int chunk = wave + c * 4;
        GLDS16(Xb + (size_t)(m0 + chunk * 16 + srow) * 1024 + skoff,
               smem + chunk * 512);
    }
    GLDS16(WT + (size_t)(n0 + wave * 16 + srow) * 1024 + skoff,
           smem + 8192 + wave * 512);

    for (int i = 0; i < 32; i++) {
        const int p = i & 1;
        __syncthreads();
        if (i < 31) {
            int k0 = (i + 1) * 32;
#pragma unroll
            for (int c = 0; c < 2; c++) {
                int chunk = wave + c * 4;
                GLDS16(Xb + (size_t)(m0 + chunk * 16 + srow) * 1024 + k0 + skoff,
                       smem + (p ^ 1) * 4096 + chunk * 512);
            }
            GLDS16(WT + (size_t)(n0 + wave * 16 + srow) * 1024 + k0 + skoff,
                   smem + 8192 + (p ^ 1) * 2048 + wave * 512);
        }
        const ushort* As = smem + p * 4096;
        const ushort* Bs = smem + 8192 + p * 2048;
        bf16x8 af[4], bfr[2];
#pragma unroll
        for (int t = 0; t < 4; t++)
            af[t] = *(const bf16x8*)&As[(wm + t * 16 + l16) * 32 + quad * 8];
#pragma unroll
        for (int t = 0; t < 2; t++)
            bfr[t] = *(const bf16x8*)&Bs[(wn + t * 16 + l16) * 32 + quad * 8];
#pragma unroll
        for (int mt = 0; mt < 4; mt++)
#pragma unroll
            for (int nt = 0; nt < 2; nt++)
                acc[mt][nt] = __builtin_amdgcn_mfma_f32_16x16x32_bf16(
                    af[mt], bfr[nt], acc[mt][nt], 0, 0, 0);
    }

#pragma unroll
    for (int mt = 0; mt < 4; mt++) {
        int row = m0 + wm + mt * 16 + quad * 4;
#pragma unroll
        for (int nt = 0; nt < 2; nt++) {
            int col = n0 + wn + nt * 16 + l16;
            float bvl = bias[col];
#pragma unroll
            for (int r = 0; r < 4; r++)
                Y[(size_t)(row + r) * 1024 + col] = acc[mt][nt][r] + bvl;
        }
    }
}

// ---------------------------------------------------------------------------
// Flash attention v8: small independent blocks. 1024 blocks x 256 thr
// (4 waves x 16 q-rows = 64 rows/block), single-buffered K/V (27.6 KB LDS)
// -> 4 resident blocks/CU = 4 INDEPENDENT barrier groups (16 waves/CU).
// Per-wave body = R10's proven code: 64-key tiles, trunc-bf16 P via
// wave-private LDS panels, softmax-lite (Q pre-scaled 1/8). XCD swizzle.
// Global loads issued before the barrier to overlap prior compute.
// ---------------------------------------------------------------------------
#define KVS 36

__global__ __launch_bounds__(256) void attn(
    const ushort* __restrict__ Q, const ushort* __restrict__ Kb,
    const ushort* __restrict__ VT, ushort* __restrict__ CTX)
{
    const int id   = blockIdx.x;
    const int g    = (id & 7) * 4 + ((id >> 3) & 3);   // (b,h) group, XCD-local
    const int qc   = id >> 5;                           // q-chunk 0..31
    const int b    = g >> 4, h = g & 15;
    const int q0   = qc * 64;
    const int tid  = threadIdx.x;
    const int lane = tid & 63, wave = tid >> 6;         // wave 0..3
    const int l16  = lane & 15, quad = lane >> 4;
    const size_t base  = (size_t)b * 2048 * 1024 + (size_t)h * 64;
    const size_t vbase = (size_t)g * 64 * 2048;

    __shared__ ushort Ks[2][64 * KVS];   // [hd-half][key][..]
    __shared__ ushort Vs[2][64 * KVS];   // [key-half][hd][..]
    __shared__ ushort Ps[4][2][16 * KVS];

    // Q A-frags (pre-scaled by 1/8 in Q GEMM)
    bf16x8 aq0, aq1;
    {
        const ushort* qp = Q + base + (size_t)(q0 + wave * 16 + l16) * 1024 + quad * 8;
        aq0 = *(const bf16x8*)qp;
        aq1 = *(const bf16x8*)(qp + 32);
    }

    f32x4 o[4] = {};
    float lsum[4] = {};

    const int srow = tid >> 2;           // 0..63
    const int soff = (tid & 3) * 8;      // 0,8,16,24

    for (int j0 = 0; j0 < 2048; j0 += 64) {
        // issue global loads first: overlap with tail of previous compute
        const ushort* kp = Kb + base + (size_t)(j0 + srow) * 1024 + soff;
        uint4 ka  = *(const uint4*)kp;
        uint4 kb2 = *(const uint4*)(kp + 32);
        const ushort* vp = VT + vbase + (size_t)srow * 2048 + j0 + soff;
        uint4 va  = *(const uint4*)vp;
        uint4 vb  = *(const uint4*)(vp + 32);

        __syncthreads();   // prev-iter readers done
        *(uint4*)&Ks[0][srow * KVS + soff] = ka;
        *(uint4*)&Ks[1][srow * KVS + soff] = kb2;
        *(uint4*)&Vs[0][srow * KVS + soff] = va;
        *(uint4*)&Vs[1][srow * KVS + soff] = vb;
        __syncthreads();   // tiles valid

        // S = Q K^T
        bf16x8 bk0[4], bk1[4];
#pragma unroll
        for (int nt = 0; nt < 4; nt++) {
            bk0[nt] = *(const bf16x8*)&Ks[0][(nt * 16 + l16) * KVS + quad * 8];
            bk1[nt] = *(const bf16x8*)&Ks[1][(nt * 16 + l16) * KVS + quad * 8];
        }
        f32x4 sacc[4] = {};
#pragma unroll
        for (int nt = 0; nt < 4; nt++) {
            sacc[nt] = __builtin_amdgcn_mfma_f32_16x16x32_bf16(aq0, bk0[nt], sacc[nt], 0, 0, 0);
            sacc[nt] = __builtin_amdgcn_mfma_f32_16x16x32_bf16(aq1, bk1[nt], sacc[nt], 0, 0, 0);
        }

        // p = exp(s) truncated to bf16; lsum from the SAME truncated value
#pragma unroll
        for (int nt = 0; nt < 4; nt++)
#pragma unroll
            for (int r = 0; r < 4; r++) {
                unsigned int u = __float_as_uint(__expf(sacc[nt][r]));
                Ps[wave][nt >> 1][(quad * 4 + r) * KVS + (nt & 1) * 16 + l16]
                    = (ushort)(u >> 16);
                lsum[r] += __uint_as_float(u & 0xffff0000u);
            }

        // O += P V  (wave-private Ps: in-wave DS ordering, no barrier)
        bf16x8 bv0[4], bv1[4];
#pragma unroll
        for (int ht = 0; ht < 4; ht++) {
            bv0[ht] = *(const bf16x8*)&Vs[0][(ht * 16 + l16) * KVS + quad * 8];
            bv1[ht] = *(const bf16x8*)&Vs[1][(ht * 16 + l16) * KVS + quad * 8];
        }
        bf16x8 ap0 = *(const bf16x8*)&Ps[wave][0][l16 * KVS + quad * 8];
        bf16x8 ap1 = *(const bf16x8*)&Ps[wave][1][l16 * KVS + quad * 8];
#pragma unroll
        for (int ht = 0; ht < 4; ht++) {
            o[ht] = __builtin_amdgcn_mfma_f32_16x16x32_bf16(ap0, bv0[ht], o[ht], 0, 0, 0);
            o[ht] = __builtin_amdgcn_mfma_f32_16x16x32_bf16(ap1, bv1[ht], o[ht], 0, 0, 0);
        }
    }

    // reduce row sums over the quad's 16 lanes; normalize; write ctx
#pragma unroll
    for (int r = 0; r < 4; r++) {
        float t = lsum[r];
#pragma unroll
        for (int d = 1; d < 16; d <<= 1) t += __shfl_xor(t, d, 64);
        float inv = 1.f / t;
        int row = q0 + wave * 16 + quad * 4 + r;
#pragma unroll
        for (int ht = 0; ht < 4; ht++)
            CTX[base + (size_t)row * 1024 + ht * 16 + l16] = f2bf(o[ht][r] * inv);
    }
}

// ---------------------------------------------------------------------------
extern "C" void kernel_launch(void* const* d_in, const int* in_sizes, int n_in,
                              void* d_out, int out_size, void* d_ws, size_t ws_size,
                              hipStream_t stream)
{
    (void)in_sizes; (void)n_in; (void)out_size; (void)ws_size;
    const float* x  = (const float*)d_in[0];
    const float* Wq = (const float*)d_in[1];
    const float* bq = (const float*)d_in[2];
    const float* Wk = (const float*)d_in[3];
    const float* bk = (const float*)d_in[4];
    const float* Wv = (const float*)d_in[5];
    const float* bv = (const float*)d_in[6];
    const float* Wo = (const float*)d_in[7];
    const float* bo = (const float*)d_in[8];

    char* ws = (char*)d_ws;
    const size_t MT = (size_t)4096 * 1024 * 2;   // 8 MB per [4096][1024] bf16
    ushort* q  = (ushort*)(ws + 0 * MT);         // q, later ctx (alias-safe)
    ushort* k  = (ushort*)(ws + 1 * MT);
    ushort* v  = (ushort*)(ws + 2 * MT);         // vT[(b*16+h)*64+hd][t]
    ushort* WT = (ushort*)(ws + 3 * MT);         // 4 x 1M bf16 (q,k,v,o stacked)
    ushort* xb = (ushort*)d_out;                 // scratch in out (dead before gemm_out)

    conv<<<dim3(4096), 256, 0, stream>>>(x, Wq, Wk, Wv, Wo, xb, WT);

    gemm_qkv<<<dim3(24, 32), 256, 0, stream>>>(xb, WT, bq, bk, bv, q, k, v);

    attn<<<dim3(1024), 256, 0, stream>>>(q, k, v, q /*ctx aliases q*/);

    gemm_out<<<dim3(16, 32), 256, 0, stream>>>(q, WT + 3 * 1048576, bo, (float*)d_out);
}

// Round 14
// 228.669 us; speedup vs baseline: 1.0026x; 1.0026x over previous
//
#include <hip/hip_runtime.h>
#include <hip/hip_bf16.h>

// MHA: B=2, T=2048, DIM=1024, H=16, HD=64. fp32 in/out, bf16 internal.
// R14 attn: combine R9's double-buffered 1-barrier staging (keeps the
// ~1300-cyc per-iter dependency chain free of global-load latency) with
// R13's small blocks: 256 thr (4 waves x 16 q-rows), LDS 45 KB ->
// 3 resident INDEPENDENT barrier groups per CU (12 waves). R9=2 groups
// w/ dbuf: 71.9us; R13=4 groups w/o dbuf: 87.7us; this = 3 groups + dbuf.
// GEMM pipeline unchanged (R11): fused QKV + XCD swizzle + DMA dbuf.

using bf16x8 = __attribute__((ext_vector_type(8))) short;   // 8 bf16 in 4 VGPRs
using f32x4  = __attribute__((ext_vector_type(4))) float;   // MFMA accumulator

static __device__ __forceinline__ unsigned short f2bf(float f) {
    unsigned int u = __float_as_uint(f);
    unsigned int r = u + 0x7fffu + ((u >> 16) & 1u);   // RNE
    return (unsigned short)(r >> 16);
}

// async global->LDS DMA, 16 B/lane; lds dst wave-uniform (HW adds lane*16)
#define GLDS16(g, l) __builtin_amdgcn_global_load_lds(                    \
    (const __attribute__((address_space(1))) void*)(g),                   \
    (__attribute__((address_space(3))) void*)(l), 16, 0, 0)

// ---------------------------------------------------------------------------
// Fused conversions: id<2048 -> x fp32->bf16; id>=2048 -> W fp32 -> WT bf16.
// ---------------------------------------------------------------------------
__global__ __launch_bounds__(256) void conv(
    const float* __restrict__ x,
    const float* __restrict__ Wq, const float* __restrict__ Wk,
    const float* __restrict__ Wv, const float* __restrict__ Wo,
    ushort* __restrict__ xb, ushort* __restrict__ WT)
{
    int id = blockIdx.x;
    if (id < 2048) {
        int i8 = (id * 256 + threadIdx.x) * 8;
        float4 a = *reinterpret_cast<const float4*>(x + i8);
        float4 b = *reinterpret_cast<const float4*>(x + i8 + 4);
        ushort t[8] = {f2bf(a.x), f2bf(a.y), f2bf(a.z), f2bf(a.w),
                       f2bf(b.x), f2bf(b.y), f2bf(b.z), f2bf(b.w)};
        *reinterpret_cast<uint4*>(xb + i8) = *reinterpret_cast<const uint4*>(t);
    } else {
        int wid = id - 2048;
        int z   = wid >> 9;
        const float* src = (z == 0) ? Wq : (z == 1) ? Wk : (z == 2) ? Wv : Wo;
        ushort* dst = WT + (size_t)z * 1024 * 1024;
        int idx = (wid & 511) * 256 + threadIdx.x;
        int n   = idx & 1023;
        int k8  = (idx >> 10) << 3;
        ushort t[8];
#pragma unroll
        for (int e = 0; e < 8; e++) t[e] = f2bf(src[(size_t)(k8 + e) * 1024 + n]);
        *reinterpret_cast<uint4*>(dst + (size_t)n * 1024 + k8) =
            *reinterpret_cast<const uint4*>(t);
    }
}

// ---------------------------------------------------------------------------
// Fused QKV GEMM (unchanged R11) -> q (scaled 1/8), k, vT. XCD-swizzled.
// ---------------------------------------------------------------------------
#define CS 136

__global__ __launch_bounds__(256) void gemm_qkv(
    const ushort* __restrict__ Xb, const ushort* __restrict__ WT,
    const float* __restrict__ bq, const float* __restrict__ bk,
    const float* __restrict__ bv,
    ushort* __restrict__ q, ushort* __restrict__ k, ushort* __restrict__ v)
{
    __shared__ ushort smem[128 * CS];

    const int tid  = threadIdx.x;
    const int lane = tid & 63, wave = tid >> 6;
    const int l16  = lane & 15, quad = lane >> 4;
    const int wm   = (wave >> 1) * 64, wn = (wave & 1) * 64;
    const int flat = blockIdx.y * 24 + blockIdx.x;
    const int xcd  = flat & 7, lid = flat >> 3;
    const int mI   = xcd * 4 + (lid & 3);
    const int nI   = lid >> 2;
    const int m0   = mI * 128;
    const int n0g  = nI * 128;
    const int srow = lane >> 2, skoff = (lane & 3) * 8;

    f32x4 acc[4][4] = {};

#pragma unroll
    for (int c = 0; c < 2; c++) {
        int chunk = wave + c * 4;
        int row   = chunk * 16 + srow;
        GLDS16(Xb + (size_t)(m0 + row) * 1024 + skoff, smem + chunk * 512);
        GLDS16(WT + (size_t)(n0g + row) * 1024 + skoff, smem + 8192 + chunk * 512);
    }

    for (int i = 0; i < 32; i++) {
        const int p = i & 1;
        __syncthreads();
        if (i < 31) {
            int k0 = (i + 1) * 32;
#pragma unroll
            for (int c = 0; c < 2; c++) {
                int chunk = wave + c * 4;
                int row   = chunk * 16 + srow;
                GLDS16(Xb + (size_t)(m0 + row) * 1024 + k0 + skoff,
                       smem + (p ^ 1) * 4096 + chunk * 512);
                GLDS16(WT + (size_t)(n0g + row) * 1024 + k0 + skoff,
                       smem + 8192 + (p ^ 1) * 4096 + chunk * 512);
            }
        }
        const ushort* As = smem + p * 4096;
        const ushort* Bs = smem + 8192 + p * 4096;
        bf16x8 af[4], bfr[4];
#pragma unroll
        for (int t = 0; t < 4; t++) {
            af[t]  = *(const bf16x8*)&As[(wm + t * 16 + l16) * 32 + quad * 8];
            bfr[t] = *(const bf16x8*)&Bs[(wn + t * 16 + l16) * 32 + quad * 8];
        }
#pragma unroll
        for (int mt = 0; mt < 4; mt++)
#pragma unroll
            for (int nt = 0; nt < 4; nt++)
                acc[mt][nt] = __builtin_amdgcn_mfma_f32_16x16x32_bf16(
                    af[mt], bfr[nt], acc[mt][nt], 0, 0, 0);
    }

    const int mat = nI >> 3;
    const int nc0 = (nI & 7) * 128;
    const float* bias = (mat == 0) ? bq : (mat == 1) ? bk : bv;

    if (mat < 2) {
        ushort* Y = (mat == 0) ? q : k;
        const float scale = (mat == 0) ? 0.125f : 1.0f;   // 1/sqrt(64) into q
#pragma unroll
        for (int mt = 0; mt < 4; mt++) {
            int row = m0 + wm + mt * 16 + quad * 4;
#pragma unroll
            for (int nt = 0; nt < 4; nt++) {
                int col = nc0 + wn + nt * 16 + l16;
                float bvl = bias[col];
#pragma unroll
                for (int r = 0; r < 4; r++)
                    Y[(size_t)(row + r) * 1024 + col] = f2bf((acc[mt][nt][r] + bvl) * scale);
            }
        }
    } else {
        __syncthreads();
#pragma unroll
        for (int mt = 0; mt < 4; mt++) {
            int rowL = wm + mt * 16 + quad * 4;
#pragma unroll
            for (int nt = 0; nt < 4; nt++) {
                int colL = wn + nt * 16 + l16;
                float bvl = bias[nc0 + colL];
                ushort t4[4];
#pragma unroll
                for (int r = 0; r < 4; r++) t4[r] = f2bf(acc[mt][nt][r] + bvl);
                *(uint2*)&smem[colL * CS + rowL] = *(const uint2*)t4;
            }
        }
        __syncthreads();
        const int bb = m0 >> 11, tB = m0 & 2047;
#pragma unroll
        for (int it = 0; it < 8; it++) {
            int hdL = it * 16 + (tid >> 4);
            int tcL = (tid & 15) * 8;
            uint4 d = *(const uint4*)&smem[hdL * CS + tcL];
            int colG = nc0 + hdL;
            int hh = colG >> 6, hd = colG & 63;
            *(uint4*)&v[(size_t)((bb * 16 + hh) * 64 + hd) * 2048 + tB + tcL] = d;
        }
    }
}

// ---------------------------------------------------------------------------
// Out-proj GEMM (unchanged R11): ctx bf16 @ WTo -> out fp32. XCD-swizzled.
// ---------------------------------------------------------------------------
__global__ __launch_bounds__(256) void gemm_out(
    const ushort* __restrict__ Xb, const ushort* __restrict__ WT,
    const float* __restrict__ bias, float* __restrict__ Y)
{
    __shared__ ushort smem[12288];

    const int tid  = threadIdx.x;
    const int lane = tid & 63, wave = tid >> 6;
    const int l16  = lane & 15, quad = lane >> 4;
    const int wm   = (wave >> 1) * 64, wn = (wave & 1) * 32;
    const int flat = blockIdx.y * 16 + blockIdx.x;
    const int xcd  = flat & 7, lid = flat >> 3;
    const int m0   = (xcd * 4 + (lid & 3)) * 128;
    const int n0   = (lid >> 2) * 64;
    const int srow = lane >> 2, skoff = (lane & 3) * 8;

    f32x4 acc[4][2] = {};

#pragma unroll
    for (int c = 0; c < 2; c++) {
        int chunk = wave + c * 4;
        GLDS16(Xb + (size_t)(m0 + chunk * 16 + srow) * 1024 + skoff,
               smem + chunk * 512);
    }
    GLDS16(WT + (size_t)(n0 + wave * 16 + srow) * 1024 + skoff,
           smem + 8192 + wave * 512);

    for (int i = 0; i < 32; i++) {
        const int p = i & 1;
        __syncthreads();
        if (i < 31) {
            int k0 = (i + 1) * 32;
#pragma unroll
            for (int c = 0; c < 2; c++) {
                int chunk = wave + c * 4;
                GLDS16(Xb + (size_t)(m0 + chunk * 16 + srow) * 1024 + k0 + skoff,
                       smem + (p ^ 1) * 4096 + chunk * 512);
            }
            GLDS16(WT + (size_t)(n0 + wave * 16 + srow) * 1024 + k0 + skoff,
                   smem + 8192 + (p ^ 1) * 2048 + wave * 512);
        }
        const ushort* As = smem + p * 4096;
        const ushort* Bs = smem + 8192 + p * 2048;
        bf16x8 af[4], bfr[2];
#pragma unroll
        for (int t = 0; t < 4; t++)
            af[t] = *(const bf16x8*)&As[(wm + t * 16 + l16) * 32 + quad * 8];
#pragma unroll
        for (int t = 0; t < 2; t++)
            bfr[t] = *(const bf16x8*)&Bs[(wn + t * 16 + l16) * 32 + quad * 8];
#pragma unroll
        for (int mt = 0; mt < 4; mt++)
#pragma unroll
            for (int nt = 0; nt < 2; nt++)
                acc[mt][nt] = __builtin_amdgcn_mfma_f32_16x16x32_bf16(
                    af[mt], bfr[nt], acc[mt][nt], 0, 0, 0);
    }

#pragma unroll
    for (int mt = 0; mt < 4; mt++) {
        int row = m0 + wm + mt * 16 + quad * 4;
#pragma unroll
        for (int nt = 0; nt < 2; nt++) {
            int col = n0 + wn + nt * 16 + l16;
            float bvl = bias[col];
#pragma unroll
            for (int r = 0; r < 4; r++)
                Y[(size_t)(row + r) * 1024 + col] = acc[mt][nt][r] + bvl;
        }
    }
}

// ---------------------------------------------------------------------------
// Flash attention v9: dbuf + small independent blocks. 1024 blocks x 256 thr
// (4 waves x 16 q-rows = 64 rows/block), double-buffered K/V (1 barrier/iter,
// loads issued right after the barrier -> staging latency off the chain),
// LDS 45 KB -> 3 independent barrier groups/CU. XCD swizzle, softmax-lite,
// trunc-bf16 P via wave-private panels. CTX aliases Q.
// ---------------------------------------------------------------------------
#define KVS 36

__global__ __launch_bounds__(256) void attn(
    const ushort* __restrict__ Q, const ushort* __restrict__ Kb,
    const ushort* __restrict__ VT, ushort* __restrict__ CTX)
{
    const int id   = blockIdx.x;
    const int g    = (id & 7) * 4 + ((id >> 3) & 3);   // (b,h) group, XCD-local
    const int qc   = id >> 5;                           // q-chunk 0..31
    const int b    = g >> 4, h = g & 15;
    const int q0   = qc * 64;
    const int tid  = threadIdx.x;
    const int lane = tid & 63, wave = tid >> 6;         // wave 0..3
    const int l16  = lane & 15, quad = lane >> 4;
    const size_t base  = (size_t)b * 2048 * 1024 + (size_t)h * 64;
    const size_t vbase = (size_t)g * 64 * 2048;

    __shared__ ushort Ks[2][2][64 * KVS];   // [buf][hd-half][key][..]  18.4 KB
    __shared__ ushort Vs[2][2][64 * KVS];   // [buf][key-half][hd][..]  18.4 KB
    __shared__ ushort Ps[4][2][16 * KVS];   // wave-private P panels     9.2 KB

    // Q A-frags (pre-scaled by 1/8 in Q GEMM)
    bf16x8 aq0, aq1;
    {
        const ushort* qp = Q + base + (size_t)(q0 + wave * 16 + l16) * 1024 + quad * 8;
        aq0 = *(const bf16x8*)qp;
        aq1 = *(const bf16x8*)(qp + 32);
    }

    f32x4 o[4] = {};
    float lsum[4] = {};

    const int srow = tid >> 2;           // 0..63
    const int soff = (tid & 3) * 8;      // 0,8,16,24

    // prologue: stage tile 0 into buffer 0
    {
        const ushort* kp = Kb + base + (size_t)srow * 1024 + soff;
        uint4 ka  = *(const uint4*)kp, kb2 = *(const uint4*)(kp + 32);
        const ushort* vp = VT + vbase + (size_t)srow * 2048 + soff;
        uint4 va  = *(const uint4*)vp, vb = *(const uint4*)(vp + 32);
        *(uint4*)&Ks[0][0][srow * KVS + soff] = ka;
        *(uint4*)&Ks[0][1][srow * KVS + soff] = kb2;
        *(uint4*)&Vs[0][0][srow * KVS + soff] = va;
        *(uint4*)&Vs[0][1][srow * KVS + soff] = vb;
    }

    for (int i = 0; i < 32; i++) {
        const int p = i & 1;
        __syncthreads();   // buf p staged; iter i-1's readers of buf p^1 done

        // issue next-tile loads immediately (landed by iter end)
        uint4 ka, kb2, va, vb;
        if (i < 31) {
            int j0 = (i + 1) * 64;
            const ushort* kp = Kb + base + (size_t)(j0 + srow) * 1024 + soff;
            ka = *(const uint4*)kp; kb2 = *(const uint4*)(kp + 32);
            const ushort* vp = VT + vbase + (size_t)srow * 2048 + j0 + soff;
            va = *(const uint4*)vp; vb = *(const uint4*)(vp + 32);
        }

        // S = Q K^T
        bf16x8 bk0[4], bk1[4];
#pragma unroll
        for (int nt = 0; nt < 4; nt++) {
            bk0[nt] = *(const bf16x8*)&Ks[p][0][(nt * 16 + l16) * KVS + quad * 8];
            bk1[nt] = *(const bf16x8*)&Ks[p][1][(nt * 16 + l16) * KVS + quad * 8];
        }
        f32x4 sacc[4] = {};
#pragma unroll
        for (int nt = 0; nt < 4; nt++) {
            sacc[nt] = __builtin_amdgcn_mfma_f32_16x16x32_bf16(aq0, bk0[nt], sacc[nt], 0, 0, 0);
            sacc[nt] = __builtin_amdgcn_mfma_f32_16x16x32_bf16(aq1, bk1[nt], sacc[nt], 0, 0, 0);
        }

        // p = exp(s) truncated to bf16; lsum from the SAME truncated value
#pragma unroll
        for (int nt = 0; nt < 4; nt++)
#pragma unroll
            for (int r = 0; r < 4; r++) {
                unsigned int u = __float_as_uint(__expf(sacc[nt][r]));
                Ps[wave][nt >> 1][(quad * 4 + r) * KVS + (nt & 1) * 16 + l16]
                    = (ushort)(u >> 16);
                lsum[r] += __uint_as_float(u & 0xffff0000u);
            }

        // O += P V  (wave-private Ps: in-wave DS ordering, no barrier)
        bf16x8 bv0[4], bv1[4];
#pragma unroll
        for (int ht = 0; ht < 4; ht++) {
            bv0[ht] = *(const bf16x8*)&Vs[p][0][(ht * 16 + l16) * KVS + quad * 8];
            bv1[ht] = *(const bf16x8*)&Vs[p][1][(ht * 16 + l16) * KVS + quad * 8];
        }
        bf16x8 ap0 = *(const bf16x8*)&Ps[wave][0][l16 * KVS + quad * 8];
        bf16x8 ap1 = *(const bf16x8*)&Ps[wave][1][l16 * KVS + quad * 8];
#pragma unroll
        for (int ht = 0; ht < 4; ht++) {
            o[ht] = __builtin_amdgcn_mfma_f32_16x16x32_bf16(ap0, bv0[ht], o[ht], 0, 0, 0);
            o[ht] = __builtin_amdgcn_mfma_f32_16x16x32_bf16(ap1, bv1[ht], o[ht], 0, 0, 0);
        }

        // stage next tile into buf p^1 (safe: see barrier comment above)
        if (i < 31) {
            *(uint4*)&Ks[p ^ 1][0][srow * KVS + soff] = ka;
            *(uint4*)&Ks[p ^ 1][1][srow * KVS + soff] = kb2;
            *(uint4*)&Vs[p ^ 1][0][srow * KVS + soff] = va;
            *(uint4*)&Vs[p ^ 1][1][srow * KVS + soff] = vb;
        }
    }

    // reduce row sums over the quad's 16 lanes; normalize; write ctx
#pragma unroll
    for (int r = 0; r < 4; r++) {
        float t = lsum[r];
#pragma unroll
        for (int d = 1; d < 16; d <<= 1) t += __shfl_xor(t, d, 64);
        float inv = 1.f / t;
        int row = q0 + wave * 16 + quad * 4 + r;
#pragma unroll
        for (int ht = 0; ht < 4; ht++)
            CTX[base + (size_t)row * 1024 + ht * 16 + l16] = f2bf(o[ht][r] * inv);
    }
}

// ---------------------------------------------------------------------------
extern "C" void kernel_launch(void* const* d_in, const int* in_sizes, int n_in,
                              void* d_out, int out_size, void* d_ws, size_t ws_size,
                              hipStream_t stream)
{
    (void)in_sizes; (void)n_in; (void)out_size; (void)ws_size;
    const float* x  = (const float*)d_in[0];
    const float* Wq = (const float*)d_in[1];
    const float* bq = (const float*)d_in[2];
    const float* Wk = (const float*)d_in[3];
    const float* bk = (const float*)d_in[4];
    const float* Wv = (const float*)d_in[5];
    const float* bv = (const float*)d_in[6];
    const float* Wo = (const float*)d_in[7];
    const float* bo = (const float*)d_in[8];

    char* ws = (char*)d_ws;
    const size_t MT = (size_t)4096 * 1024 * 2;   // 8 MB per [4096][1024] bf16
    ushort* q  = (ushort*)(ws + 0 * MT);         // q, later ctx (alias-safe)
    ushort* k  = (ushort*)(ws + 1 * MT);
    ushort* v  = (ushort*)(ws + 2 * MT);         // vT[(b*16+h)*64+hd][t]
    ushort* WT = (ushort*)(ws + 3 * MT);         // 4 x 1M bf16 (q,k,v,o stacked)
    ushort* xb = (ushort*)d_out;                 // scratch in out (dead before gemm_out)

    conv<<<dim3(4096), 256, 0, stream>>>(x, Wq, Wk, Wv, Wo, xb, WT);

    gemm_qkv<<<dim3(24, 32), 256, 0, stream>>>(xb, WT, bq, bk, bv, q, k, v);

    attn<<<dim3(1024), 256, 0, stream>>>(q, k, v, q /*ctx aliases q*/);

    gemm_out<<<dim3(16, 32), 256, 0, stream>>>(q, WT + 3 * 1048576, bo, (float*)d_out);
}

// Round 15
// 227.567 us; speedup vs baseline: 1.0075x; 1.0048x over previous
//
#include <hip/hip_runtime.h>
#include <hip/hip_bf16.h>

// MHA: B=2, T=2048, DIM=1024, H=16, HD=64. fp32 in/out, bf16 internal.
// R15: attn reverted to R9-exact (empirical optimum over R9-R14 sweep:
// 128 q-rows/block, 4 waves x 32 rows, dbuf K/V, 1 barrier/iter, 512 blocks)
// + two VALU trims: log2(e) folded into Q scale -> raw exp2f (kills hidden
// per-exp v_mul), lsum from full-precision p (kills AND-mask op).
// GEMMs at m97-structure ceiling for K=1024 (~350 TF, m102) - unchanged.

using bf16x8 = __attribute__((ext_vector_type(8))) short;   // 8 bf16 in 4 VGPRs
using f32x4  = __attribute__((ext_vector_type(4))) float;   // MFMA accumulator

static __device__ __forceinline__ unsigned short f2bf(float f) {
    unsigned int u = __float_as_uint(f);
    unsigned int r = u + 0x7fffu + ((u >> 16) & 1u);   // RNE
    return (unsigned short)(r >> 16);
}

// async global->LDS DMA, 16 B/lane; lds dst wave-uniform (HW adds lane*16)
#define GLDS16(g, l) __builtin_amdgcn_global_load_lds(                    \
    (const __attribute__((address_space(1))) void*)(g),                   \
    (__attribute__((address_space(3))) void*)(l), 16, 0, 0)

// ---------------------------------------------------------------------------
// Fused conversions: id<2048 -> x fp32->bf16; id>=2048 -> W fp32 -> WT bf16.
// ---------------------------------------------------------------------------
__global__ __launch_bounds__(256) void conv(
    const float* __restrict__ x,
    const float* __restrict__ Wq, const float* __restrict__ Wk,
    const float* __restrict__ Wv, const float* __restrict__ Wo,
    ushort* __restrict__ xb, ushort* __restrict__ WT)
{
    int id = blockIdx.x;
    if (id < 2048) {
        int i8 = (id * 256 + threadIdx.x) * 8;
        float4 a = *reinterpret_cast<const float4*>(x + i8);
        float4 b = *reinterpret_cast<const float4*>(x + i8 + 4);
        ushort t[8] = {f2bf(a.x), f2bf(a.y), f2bf(a.z), f2bf(a.w),
                       f2bf(b.x), f2bf(b.y), f2bf(b.z), f2bf(b.w)};
        *reinterpret_cast<uint4*>(xb + i8) = *reinterpret_cast<const uint4*>(t);
    } else {
        int wid = id - 2048;
        int z   = wid >> 9;
        const float* src = (z == 0) ? Wq : (z == 1) ? Wk : (z == 2) ? Wv : Wo;
        ushort* dst = WT + (size_t)z * 1024 * 1024;
        int idx = (wid & 511) * 256 + threadIdx.x;
        int n   = idx & 1023;
        int k8  = (idx >> 10) << 3;
        ushort t[8];
#pragma unroll
        for (int e = 0; e < 8; e++) t[e] = f2bf(src[(size_t)(k8 + e) * 1024 + n]);
        *reinterpret_cast<uint4*>(dst + (size_t)n * 1024 + k8) =
            *reinterpret_cast<const uint4*>(t);
    }
}

// ---------------------------------------------------------------------------
// Fused QKV GEMM (R11) -> q (scaled 0.125*log2e), k, vT. XCD-swizzled.
// ---------------------------------------------------------------------------
#define CS 136

__global__ __launch_bounds__(256) void gemm_qkv(
    const ushort* __restrict__ Xb, const ushort* __restrict__ WT,
    const float* __restrict__ bq, const float* __restrict__ bk,
    const float* __restrict__ bv,
    ushort* __restrict__ q, ushort* __restrict__ k, ushort* __restrict__ v)
{
    __shared__ ushort smem[128 * CS];

    const int tid  = threadIdx.x;
    const int lane = tid & 63, wave = tid >> 6;
    const int l16  = lane & 15, quad = lane >> 4;
    const int wm   = (wave >> 1) * 64, wn = (wave & 1) * 64;
    const int flat = blockIdx.y * 24 + blockIdx.x;
    const int xcd  = flat & 7, lid = flat >> 3;
    const int mI   = xcd * 4 + (lid & 3);
    const int nI   = lid >> 2;
    const int m0   = mI * 128;
    const int n0g  = nI * 128;
    const int srow = lane >> 2, skoff = (lane & 3) * 8;

    f32x4 acc[4][4] = {};

#pragma unroll
    for (int c = 0; c < 2; c++) {
        int chunk = wave + c * 4;
        int row   = chunk * 16 + srow;
        GLDS16(Xb + (size_t)(m0 + row) * 1024 + skoff, smem + chunk * 512);
        GLDS16(WT + (size_t)(n0g + row) * 1024 + skoff, smem + 8192 + chunk * 512);
    }

    for (int i = 0; i < 32; i++) {
        const int p = i & 1;
        __syncthreads();
        if (i < 31) {
            int k0 = (i + 1) * 32;
#pragma unroll
            for (int c = 0; c < 2; c++) {
                int chunk = wave + c * 4;
                int row   = chunk * 16 + srow;
                GLDS16(Xb + (size_t)(m0 + row) * 1024 + k0 + skoff,
                       smem + (p ^ 1) * 4096 + chunk * 512);
                GLDS16(WT + (size_t)(n0g + row) * 1024 + k0 + skoff,
                       smem + 8192 + (p ^ 1) * 4096 + chunk * 512);
            }
        }
        const ushort* As = smem + p * 4096;
        const ushort* Bs = smem + 8192 + p * 4096;
        bf16x8 af[4], bfr[4];
#pragma unroll
        for (int t = 0; t < 4; t++) {
            af[t]  = *(const bf16x8*)&As[(wm + t * 16 + l16) * 32 + quad * 8];
            bfr[t] = *(const bf16x8*)&Bs[(wn + t * 16 + l16) * 32 + quad * 8];
        }
#pragma unroll
        for (int mt = 0; mt < 4; mt++)
#pragma unroll
            for (int nt = 0; nt < 4; nt++)
                acc[mt][nt] = __builtin_amdgcn_mfma_f32_16x16x32_bf16(
                    af[mt], bfr[nt], acc[mt][nt], 0, 0, 0);
    }

    const int mat = nI >> 3;
    const int nc0 = (nI & 7) * 128;
    const float* bias = (mat == 0) ? bq : (mat == 1) ? bk : bv;

    if (mat < 2) {
        ushort* Y = (mat == 0) ? q : k;
        // q pre-scaled by (1/sqrt(64)) * log2(e) so attn uses raw exp2
        const float scale = (mat == 0) ? 0.18033688f : 1.0f;
#pragma unroll
        for (int mt = 0; mt < 4; mt++) {
            int row = m0 + wm + mt * 16 + quad * 4;
#pragma unroll
            for (int nt = 0; nt < 4; nt++) {
                int col = nc0 + wn + nt * 16 + l16;
                float bvl = bias[col];
#pragma unroll
                for (int r = 0; r < 4; r++)
                    Y[(size_t)(row + r) * 1024 + col] = f2bf((acc[mt][nt][r] + bvl) * scale);
            }
        }
    } else {
        __syncthreads();
#pragma unroll
        for (int mt = 0; mt < 4; mt++) {
            int rowL = wm + mt * 16 + quad * 4;
#pragma unroll
            for (int nt = 0; nt < 4; nt++) {
                int colL = wn + nt * 16 + l16;
                float bvl = bias[nc0 + colL];
                ushort t4[4];
#pragma unroll
                for (int r = 0; r < 4; r++) t4[r] = f2bf(acc[mt][nt][r] + bvl);
                *(uint2*)&smem[colL * CS + rowL] = *(const uint2*)t4;
            }
        }
        __syncthreads();
        const int bb = m0 >> 11, tB = m0 & 2047;
#pragma unroll
        for (int it = 0; it < 8; it++) {
            int hdL = it * 16 + (tid >> 4);
            int tcL = (tid & 15) * 8;
            uint4 d = *(const uint4*)&smem[hdL * CS + tcL];
            int colG = nc0 + hdL;
            int hh = colG >> 6, hd = colG & 63;
            *(uint4*)&v[(size_t)((bb * 16 + hh) * 64 + hd) * 2048 + tB + tcL] = d;
        }
    }
}

// ---------------------------------------------------------------------------
// Out-proj GEMM (R11): ctx bf16 @ WTo -> out fp32. XCD-swizzled.
// ---------------------------------------------------------------------------
__global__ __launch_bounds__(256) void gemm_out(
    const ushort* __restrict__ Xb, const ushort* __restrict__ WT,
    const float* __restrict__ bias, float* __restrict__ Y)
{
    __shared__ ushort smem[12288];

    const int tid  = threadIdx.x;
    const int lane = tid & 63, wave = tid >> 6;
    const int l16  = lane & 15, quad = lane >> 4;
    const int wm   = (wave >> 1) * 64, wn = (wave & 1) * 32;
    const int flat = blockIdx.y * 16 + blockIdx.x;
    const int xcd  = flat & 7, lid = flat >> 3;
    const int m0   = (xcd * 4 + (lid & 3)) * 128;
    const int n0   = (lid >> 2) * 64;
    const int srow = lane >> 2, skoff = (lane & 3) * 8;

    f32x4 acc[4][2] = {};

#pragma unroll
    for (int c = 0; c < 2; c++) {
        int chunk = wave + c * 4;
        GLDS16(Xb + (size_t)(m0 + chunk * 16 + srow) * 1024 + skoff,
               smem + chunk * 512);
    }
    GLDS16(WT + (size_t)(n0 + wave * 16 + srow) * 1024 + skoff,
           smem + 8192 + wave * 512);

    for (int i = 0; i < 32; i++) {
        const int p = i & 1;
        __syncthreads();
        if (i < 31) {
            int k0 = (i + 1) * 32;
#pragma unroll
            for (int c = 0; c < 2; c++) {
                int chunk = wave + c * 4;
                GLDS16(Xb + (size_t)(m0 + chunk * 16 + srow) * 1024 + k0 + skoff,
                       smem + (p ^ 1) * 4096 + chunk * 512);
            }
            GLDS16(WT + (size_t)(n0 + wave * 16 + srow) * 1024 + k0 + skoff,
                   smem + 8192 + (p ^ 1) * 2048 + wave * 512);
        }
        const ushort* As = smem + p * 4096;
        const ushort* Bs = smem + 8192 + p * 2048;
        bf16x8 af[4], bfr[2];
#pragma unroll
        for (int t = 0; t < 4; t++)
            af[t] = *(const bf16x8*)&As[(wm + t * 16 + l16) * 32 + quad * 8];
#pragma unroll
        for (int t = 0; t < 2; t++)
            bfr[t] = *(const bf16x8*)&Bs[(wn + t * 16 + l16) * 32 + quad * 8];
#pragma unroll
        for (int mt = 0; mt < 4; mt++)
#pragma unroll
            for (int nt = 0; nt < 2; nt++)
                acc[mt][nt] = __builtin_amdgcn_mfma_f32_16x16x32_bf16(
                    af[mt], bfr[nt], acc[mt][nt], 0, 0, 0);
    }

#pragma unroll
    for (int mt = 0; mt < 4; mt++) {
        int row = m0 + wm + mt * 16 + quad * 4;
#pragma unroll
        for (int nt = 0; nt < 2; nt++) {
            int col = n0 + wn + nt * 16 + l16;
            float bvl = bias[col];
#pragma unroll
            for (int r = 0; r < 4; r++)
                Y[(size_t)(row + r) * 1024 + col] = acc[mt][nt][r] + bvl;
        }
    }
}

// ---------------------------------------------------------------------------
// Flash attention (R9-exact structure): 512 blocks x 256 thr, 4 waves x
// 32 q-rows, double-buffered K/V, 1 barrier/iter, XCD swizzle, wave-private
// P panels. Trims: raw exp2f (log2e pre-folded into q), fp32 lsum.
// ---------------------------------------------------------------------------
#define KVS 36

__global__ __launch_bounds__(256) void attn(
    const ushort* __restrict__ Q, const ushort* __restrict__ Kb,
    const ushort* __restrict__ VT, ushort* __restrict__ CTX)
{
    const int id   = blockIdx.x;
    const int g    = (id & 7) * 4 + ((id >> 3) & 3);   // (b,h) group, XCD-local
    const int qc   = id >> 5;                           // q-chunk 0..15
    const int b    = g >> 4, h = g & 15;
    const int q0   = qc * 128;
    const int tid  = threadIdx.x;
    const int lane = tid & 63, wave = tid >> 6;
    const int l16  = lane & 15, quad = lane >> 4;
    const int wq   = wave * 32;
    const size_t base  = (size_t)b * 2048 * 1024 + (size_t)h * 64;
    const size_t vbase = (size_t)g * 64 * 2048;

    __shared__ ushort Ks[2][2][64 * KVS];   // [buf][hd-half][key][..]
    __shared__ ushort Vs[2][2][64 * KVS];   // [buf][key-half][hd][..]
    __shared__ ushort Ps[4][2][32 * KVS];   // wave-private P panels

    // Q A-frags (pre-scaled by 0.125*log2e in the Q GEMM)
    bf16x8 aq[2][2];
#pragma unroll
    for (int rt = 0; rt < 2; rt++) {
        const ushort* qp = Q + base + (size_t)(q0 + wq + rt * 16 + l16) * 1024 + quad * 8;
        aq[rt][0] = *(const bf16x8*)qp;
        aq[rt][1] = *(const bf16x8*)(qp + 32);
    }

    f32x4 o[2][4] = {};
    float lsum[2][4] = {};

    const int srow = tid >> 2;          // 0..63
    const int soff = (tid & 3) * 8;     // 0,8,16,24

    // prologue: stage tile 0 into buffer 0
    {
        const ushort* kp = Kb + base + (size_t)srow * 1024 + soff;
        uint4 ka = *(const uint4*)kp, kb2 = *(const uint4*)(kp + 32);
        const ushort* vp = VT + vbase + (size_t)srow * 2048 + soff;
        uint4 va = *(const uint4*)vp, vb = *(const uint4*)(vp + 32);
        *(uint4*)&Ks[0][0][srow * KVS + soff] = ka;
        *(uint4*)&Ks[0][1][srow * KVS + soff] = kb2;
        *(uint4*)&Vs[0][0][srow * KVS + soff] = va;
        *(uint4*)&Vs[0][1][srow * KVS + soff] = vb;
    }

    for (int i = 0; i < 32; i++) {
        const int p = i & 1;
        __syncthreads();   // buf p staged + old readers of buf p^1 done

        // issue next-tile loads immediately (consumed at iter end)
        uint4 ka, kb2, va, vb;
        if (i < 31) {
            int j0 = (i + 1) * 64;
            const ushort* kp = Kb + base + (size_t)(j0 + srow) * 1024 + soff;
            ka = *(const uint4*)kp; kb2 = *(const uint4*)(kp + 32);
            const ushort* vp = VT + vbase + (size_t)srow * 2048 + j0 + soff;
            va = *(const uint4*)vp; vb = *(const uint4*)(vp + 32);
        }

        // S = Q K^T
        bf16x8 bk0[4], bk1[4];
#pragma unroll
        for (int nt = 0; nt < 4; nt++) {
            bk0[nt] = *(const bf16x8*)&Ks[p][0][(nt * 16 + l16) * KVS + quad * 8];
            bk1[nt] = *(const bf16x8*)&Ks[p][1][(nt * 16 + l16) * KVS + quad * 8];
        }
        f32x4 sacc[2][4] = {};
#pragma unroll
        for (int rt = 0; rt < 2; rt++)
#pragma unroll
            for (int nt = 0; nt < 4; nt++) {
                sacc[rt][nt] = __builtin_amdgcn_mfma_f32_16x16x32_bf16(
                    aq[rt][0], bk0[nt], sacc[rt][nt], 0, 0, 0);
                sacc[rt][nt] = __builtin_amdgcn_mfma_f32_16x16x32_bf16(
                    aq[rt][1], bk1[nt], sacc[rt][nt], 0, 0, 0);
            }

        // p = exp2(s) (log2e pre-folded); lsum fp32; P truncated to bf16
#pragma unroll
        for (int rt = 0; rt < 2; rt++)
#pragma unroll
            for (int nt = 0; nt < 4; nt++)
#pragma unroll
                for (int r = 0; r < 4; r++) {
                    float pv = exp2f(sacc[rt][nt][r]);
                    lsum[rt][r] += pv;
                    Ps[wave][nt >> 1][(rt * 16 + quad * 4 + r) * KVS + (nt & 1) * 16 + l16]
                        = (ushort)(__float_as_uint(pv) >> 16);
                }

        // O += P V (wave-private Ps: in-wave DS ordering, no barrier)
        bf16x8 bv0[4], bv1[4], ap[2][2];
#pragma unroll
        for (int ht = 0; ht < 4; ht++) {
            bv0[ht] = *(const bf16x8*)&Vs[p][0][(ht * 16 + l16) * KVS + quad * 8];
            bv1[ht] = *(const bf16x8*)&Vs[p][1][(ht * 16 + l16) * KVS + quad * 8];
        }
#pragma unroll
        for (int rt = 0; rt < 2; rt++) {
            ap[rt][0] = *(const bf16x8*)&Ps[wave][0][(rt * 16 + l16) * KVS + quad * 8];
            ap[rt][1] = *(const bf16x8*)&Ps[wave][1][(rt * 16 + l16) * KVS + quad * 8];
        }
#pragma unroll
        for (int rt = 0; rt < 2; rt++)
#pragma unroll
            for (int ht = 0; ht < 4; ht++) {
                o[rt][ht] = __builtin_amdgcn_mfma_f32_16x16x32_bf16(
                    ap[rt][0], bv0[ht], o[rt][ht], 0, 0, 0);
                o[rt][ht] = __builtin_amdgcn_mfma_f32_16x16x32_bf16(
                    ap[rt][1], bv1[ht], o[rt][ht], 0, 0, 0);
            }

        // stage next tile into buf p^1
        if (i < 31) {
            *(uint4*)&Ks[p ^ 1][0][srow * KVS + soff] = ka;
            *(uint4*)&Ks[p ^ 1][1][srow * KVS + soff] = kb2;
            *(uint4*)&Vs[p ^ 1][0][srow * KVS + soff] = va;
            *(uint4*)&Vs[p ^ 1][1][srow * KVS + soff] = vb;
        }
    }

    // reduce row sums over the quad's 16 lanes; normalize; write ctx
#pragma unroll
    for (int rt = 0; rt < 2; rt++)
#pragma unroll
        for (int r = 0; r < 4; r++) {
            float t = lsum[rt][r];
#pragma unroll
            for (int d = 1; d < 16; d <<= 1) t += __shfl_xor(t, d, 64);
            float inv = 1.f / t;
            int row = q0 + wq + rt * 16 + quad * 4 + r;
#pragma unroll
            for (int ht = 0; ht < 4; ht++)
                CTX[base + (size_t)row * 1024 + ht * 16 + l16] = f2bf(o[rt][ht][r] * inv);
        }
}

// ---------------------------------------------------------------------------
extern "C" void kernel_launch(void* const* d_in, const int* in_sizes, int n_in,
                              void* d_out, int out_size, void* d_ws, size_t ws_size,
                              hipStream_t stream)
{
    (void)in_sizes; (void)n_in; (void)out_size; (void)ws_size;
    const float* x  = (const float*)d_in[0];
    const float* Wq = (const float*)d_in[1];
    const float* bq = (const float*)d_in[2];
    const float* Wk = (const float*)d_in[3];
    const float* bk = (const float*)d_in[4];
    const float* Wv = (const float*)d_in[5];
    const float* bv = (const float*)d_in[6];
    const float* Wo = (const float*)d_in[7];
    const float* bo = (const float*)d_in[8];

    char* ws = (char*)d_ws;
    const size_t MT = (size_t)4096 * 1024 * 2;   // 8 MB per [4096][1024] bf16
    ushort* q  = (ushort*)(ws + 0 * MT);         // q, later ctx (alias-safe)
    ushort* k  = (ushort*)(ws + 1 * MT);
    ushort* v  = (ushort*)(ws + 2 * MT);         // vT[(b*16+h)*64+hd][t]
    ushort* WT = (ushort*)(ws + 3 * MT);         // 4 x 1M bf16 (q,k,v,o stacked)
    ushort* xb = (ushort*)d_out;                 // scratch in out (dead before gemm_out)

    conv<<<dim3(4096), 256, 0, stream>>>(x, Wq, Wk, Wv, Wo, xb, WT);

    gemm_qkv<<<dim3(24, 32), 256, 0, stream>>>(xb, WT, bq, bk, bv, q, k, v);

    attn<<<dim3(512), 256, 0, stream>>>(q, k, v, q /*ctx aliases q*/);

    gemm_out<<<dim3(16, 32), 256, 0, stream>>>(q, WT + 3 * 1048576, bo, (float*)d_out);
}

// Round 16
// 213.855 us; speedup vs baseline: 1.0721x; 1.0641x over previous
//
#include <hip/hip_runtime.h>
#include <hip/hip_bf16.h>

// MHA: B=2, T=2048, DIM=1024, H=16, HD=64. fp32 in/out, bf16 internal.
// R16: single fix over R15 — exp2f (libm, precision-guarded OCML path:
// +VALU ops, +12 VGPR, attn 71.9->83.7 regression) replaced with
// __builtin_amdgcn_exp2f = raw v_exp_f32. log2e stays folded into Q scale,
// so softmax exp costs exactly ONE instruction (R9 paid v_mul+v_exp).
// Structure = R9-exact attn (empirical optimum of R9-R14 sweep) + R11 GEMMs.

using bf16x8 = __attribute__((ext_vector_type(8))) short;   // 8 bf16 in 4 VGPRs
using f32x4  = __attribute__((ext_vector_type(4))) float;   // MFMA accumulator

static __device__ __forceinline__ unsigned short f2bf(float f) {
    unsigned int u = __float_as_uint(f);
    unsigned int r = u + 0x7fffu + ((u >> 16) & 1u);   // RNE
    return (unsigned short)(r >> 16);
}

// async global->LDS DMA, 16 B/lane; lds dst wave-uniform (HW adds lane*16)
#define GLDS16(g, l) __builtin_amdgcn_global_load_lds(                    \
    (const __attribute__((address_space(1))) void*)(g),                   \
    (__attribute__((address_space(3))) void*)(l), 16, 0, 0)

// ---------------------------------------------------------------------------
// Fused conversions: id<2048 -> x fp32->bf16; id>=2048 -> W fp32 -> WT bf16.
// ---------------------------------------------------------------------------
__global__ __launch_bounds__(256) void conv(
    const float* __restrict__ x,
    const float* __restrict__ Wq, const float* __restrict__ Wk,
    const float* __restrict__ Wv, const float* __restrict__ Wo,
    ushort* __restrict__ xb, ushort* __restrict__ WT)
{
    int id = blockIdx.x;
    if (id < 2048) {
        int i8 = (id * 256 + threadIdx.x) * 8;
        float4 a = *reinterpret_cast<const float4*>(x + i8);
        float4 b = *reinterpret_cast<const float4*>(x + i8 + 4);
        ushort t[8] = {f2bf(a.x), f2bf(a.y), f2bf(a.z), f2bf(a.w),
                       f2bf(b.x), f2bf(b.y), f2bf(b.z), f2bf(b.w)};
        *reinterpret_cast<uint4*>(xb + i8) = *reinterpret_cast<const uint4*>(t);
    } else {
        int wid = id - 2048;
        int z   = wid >> 9;
        const float* src = (z == 0) ? Wq : (z == 1) ? Wk : (z == 2) ? Wv : Wo;
        ushort* dst = WT + (size_t)z * 1024 * 1024;
        int idx = (wid & 511) * 256 + threadIdx.x;
        int n   = idx & 1023;
        int k8  = (idx >> 10) << 3;
        ushort t[8];
#pragma unroll
        for (int e = 0; e < 8; e++) t[e] = f2bf(src[(size_t)(k8 + e) * 1024 + n]);
        *reinterpret_cast<uint4*>(dst + (size_t)n * 1024 + k8) =
            *reinterpret_cast<const uint4*>(t);
    }
}

// ---------------------------------------------------------------------------
// Fused QKV GEMM (R11) -> q (scaled 0.125*log2e), k, vT. XCD-swizzled.
// ---------------------------------------------------------------------------
#define CS 136

__global__ __launch_bounds__(256) void gemm_qkv(
    const ushort* __restrict__ Xb, const ushort* __restrict__ WT,
    const float* __restrict__ bq, const float* __restrict__ bk,
    const float* __restrict__ bv,
    ushort* __restrict__ q, ushort* __restrict__ k, ushort* __restrict__ v)
{
    __shared__ ushort smem[128 * CS];

    const int tid  = threadIdx.x;
    const int lane = tid & 63, wave = tid >> 6;
    const int l16  = lane & 15, quad = lane >> 4;
    const int wm   = (wave >> 1) * 64, wn = (wave & 1) * 64;
    const int flat = blockIdx.y * 24 + blockIdx.x;
    const int xcd  = flat & 7, lid = flat >> 3;
    const int mI   = xcd * 4 + (lid & 3);
    const int nI   = lid >> 2;
    const int m0   = mI * 128;
    const int n0g  = nI * 128;
    const int srow = lane >> 2, skoff = (lane & 3) * 8;

    f32x4 acc[4][4] = {};

#pragma unroll
    for (int c = 0; c < 2; c++) {
        int chunk = wave + c * 4;
        int row   = chunk * 16 + srow;
        GLDS16(Xb + (size_t)(m0 + row) * 1024 + skoff, smem + chunk * 512);
        GLDS16(WT + (size_t)(n0g + row) * 1024 + skoff, smem + 8192 + chunk * 512);
    }

    for (int i = 0; i < 32; i++) {
        const int p = i & 1;
        __syncthreads();
        if (i < 31) {
            int k0 = (i + 1) * 32;
#pragma unroll
            for (int c = 0; c < 2; c++) {
                int chunk = wave + c * 4;
                int row   = chunk * 16 + srow;
                GLDS16(Xb + (size_t)(m0 + row) * 1024 + k0 + skoff,
                       smem + (p ^ 1) * 4096 + chunk * 512);
                GLDS16(WT + (size_t)(n0g + row) * 1024 + k0 + skoff,
                       smem + 8192 + (p ^ 1) * 4096 + chunk * 512);
            }
        }
        const ushort* As = smem + p * 4096;
        const ushort* Bs = smem + 8192 + p * 4096;
        bf16x8 af[4], bfr[4];
#pragma unroll
        for (int t = 0; t < 4; t++) {
            af[t]  = *(const bf16x8*)&As[(wm + t * 16 + l16) * 32 + quad * 8];
            bfr[t] = *(const bf16x8*)&Bs[(wn + t * 16 + l16) * 32 + quad * 8];
        }
#pragma unroll
        for (int mt = 0; mt < 4; mt++)
#pragma unroll
            for (int nt = 0; nt < 4; nt++)
                acc[mt][nt] = __builtin_amdgcn_mfma_f32_16x16x32_bf16(
                    af[mt], bfr[nt], acc[mt][nt], 0, 0, 0);
    }

    const int mat = nI >> 3;
    const int nc0 = (nI & 7) * 128;
    const float* bias = (mat == 0) ? bq : (mat == 1) ? bk : bv;

    if (mat < 2) {
        ushort* Y = (mat == 0) ? q : k;
        // q pre-scaled by (1/sqrt(64)) * log2(e) so attn uses raw v_exp_f32
        const float scale = (mat == 0) ? 0.18033688f : 1.0f;
#pragma unroll
        for (int mt = 0; mt < 4; mt++) {
            int row = m0 + wm + mt * 16 + quad * 4;
#pragma unroll
            for (int nt = 0; nt < 4; nt++) {
                int col = nc0 + wn + nt * 16 + l16;
                float bvl = bias[col];
#pragma unroll
                for (int r = 0; r < 4; r++)
                    Y[(size_t)(row + r) * 1024 + col] = f2bf((acc[mt][nt][r] + bvl) * scale);
            }
        }
    } else {
        __syncthreads();
#pragma unroll
        for (int mt = 0; mt < 4; mt++) {
            int rowL = wm + mt * 16 + quad * 4;
#pragma unroll
            for (int nt = 0; nt < 4; nt++) {
                int colL = wn + nt * 16 + l16;
                float bvl = bias[nc0 + colL];
                ushort t4[4];
#pragma unroll
                for (int r = 0; r < 4; r++) t4[r] = f2bf(acc[mt][nt][r] + bvl);
                *(uint2*)&smem[colL * CS + rowL] = *(const uint2*)t4;
            }
        }
        __syncthreads();
        const int bb = m0 >> 11, tB = m0 & 2047;
#pragma unroll
        for (int it = 0; it < 8; it++) {
            int hdL = it * 16 + (tid >> 4);
            int tcL = (tid & 15) * 8;
            uint4 d = *(const uint4*)&smem[hdL * CS + tcL];
            int colG = nc0 + hdL;
            int hh = colG >> 6, hd = colG & 63;
            *(uint4*)&v[(size_t)((bb * 16 + hh) * 64 + hd) * 2048 + tB + tcL] = d;
        }
    }
}

// ---------------------------------------------------------------------------
// Out-proj GEMM (R11): ctx bf16 @ WTo -> out fp32. XCD-swizzled.
// ---------------------------------------------------------------------------
__global__ __launch_bounds__(256) void gemm_out(
    const ushort* __restrict__ Xb, const ushort* __restrict__ WT,
    const float* __restrict__ bias, float* __restrict__ Y)
{
    __shared__ ushort smem[12288];

    const int tid  = threadIdx.x;
    const int lane = tid & 63, wave = tid >> 6;
    const int l16  = lane & 15, quad = lane >> 4;
    const int wm   = (wave >> 1) * 64, wn = (wave & 1) * 32;
    const int flat = blockIdx.y * 16 + blockIdx.x;
    const int xcd  = flat & 7, lid = flat >> 3;
    const int m0   = (xcd * 4 + (lid & 3)) * 128;
    const int n0   = (lid >> 2) * 64;
    const int srow = lane >> 2, skoff = (lane & 3) * 8;

    f32x4 acc[4][2] = {};

#pragma unroll
    for (int c = 0; c < 2; c++) {
        int chunk = wave + c * 4;
        GLDS16(Xb + (size_t)(m0 + chunk * 16 + srow) * 1024 + skoff,
               smem + chunk * 512);
    }
    GLDS16(WT + (size_t)(n0 + wave * 16 + srow) * 1024 + skoff,
           smem + 8192 + wave * 512);

    for (int i = 0; i < 32; i++) {
        const int p = i & 1;
        __syncthreads();
        if (i < 31) {
            int k0 = (i + 1) * 32;
#pragma unroll
            for (int c = 0; c < 2; c++) {
                int chunk = wave + c * 4;
                GLDS16(Xb + (size_t)(m0 + chunk * 16 + srow) * 1024 + k0 + skoff,
                       smem + (p ^ 1) * 4096 + chunk * 512);
            }
            GLDS16(WT + (size_t)(n0 + wave * 16 + srow) * 1024 + k0 + skoff,
                   smem + 8192 + (p ^ 1) * 2048 + wave * 512);
        }
        const ushort* As = smem + p * 4096;
        const ushort* Bs = smem + 8192 + p * 2048;
        bf16x8 af[4], bfr[2];
#pragma unroll
        for (int t = 0; t < 4; t++)
            af[t] = *(const bf16x8*)&As[(wm + t * 16 + l16) * 32 + quad * 8];
#pragma unroll
        for (int t = 0; t < 2; t++)
            bfr[t] = *(const bf16x8*)&Bs[(wn + t * 16 + l16) * 32 + quad * 8];
#pragma unroll
        for (int mt = 0; mt < 4; mt++)
#pragma unroll
            for (int nt = 0; nt < 2; nt++)
                acc[mt][nt] = __builtin_amdgcn_mfma_f32_16x16x32_bf16(
                    af[mt], bfr[nt], acc[mt][nt], 0, 0, 0);
    }

#pragma unroll
    for (int mt = 0; mt < 4; mt++) {
        int row = m0 + wm + mt * 16 + quad * 4;
#pragma unroll
        for (int nt = 0; nt < 2; nt++) {
            int col = n0 + wn + nt * 16 + l16;
            float bvl = bias[col];
#pragma unroll
            for (int r = 0; r < 4; r++)
                Y[(size_t)(row + r) * 1024 + col] = acc[mt][nt][r] + bvl;
        }
    }
}

// ---------------------------------------------------------------------------
// Flash attention (R9-exact structure): 512 blocks x 256 thr, 4 waves x
// 32 q-rows, double-buffered K/V, 1 barrier/iter, XCD swizzle, wave-private
// P panels. exp = __builtin_amdgcn_exp2f (raw v_exp_f32; log2e pre-folded).
// ---------------------------------------------------------------------------
#define KVS 36

__global__ __launch_bounds__(256) void attn(
    const ushort* __restrict__ Q, const ushort* __restrict__ Kb,
    const ushort* __restrict__ VT, ushort* __restrict__ CTX)
{
    const int id   = blockIdx.x;
    const int g    = (id & 7) * 4 + ((id >> 3) & 3);   // (b,h) group, XCD-local
    const int qc   = id >> 5;                           // q-chunk 0..15
    const int b    = g >> 4, h = g & 15;
    const int q0   = qc * 128;
    const int tid  = threadIdx.x;
    const int lane = tid & 63, wave = tid >> 6;
    const int l16  = lane & 15, quad = lane >> 4;
    const int wq   = wave * 32;
    const size_t base  = (size_t)b * 2048 * 1024 + (size_t)h * 64;
    const size_t vbase = (size_t)g * 64 * 2048;

    __shared__ ushort Ks[2][2][64 * KVS];   // [buf][hd-half][key][..]
    __shared__ ushort Vs[2][2][64 * KVS];   // [buf][key-half][hd][..]
    __shared__ ushort Ps[4][2][32 * KVS];   // wave-private P panels

    // Q A-frags (pre-scaled by 0.125*log2e in the Q GEMM)
    bf16x8 aq[2][2];
#pragma unroll
    for (int rt = 0; rt < 2; rt++) {
        const ushort* qp = Q + base + (size_t)(q0 + wq + rt * 16 + l16) * 1024 + quad * 8;
        aq[rt][0] = *(const bf16x8*)qp;
        aq[rt][1] = *(const bf16x8*)(qp + 32);
    }

    f32x4 o[2][4] = {};
    float lsum[2][4] = {};

    const int srow = tid >> 2;          // 0..63
    const int soff = (tid & 3) * 8;     // 0,8,16,24

    // prologue: stage tile 0 into buffer 0
    {
        const ushort* kp = Kb + base + (size_t)srow * 1024 + soff;
        uint4 ka = *(const uint4*)kp, kb2 = *(const uint4*)(kp + 32);
        const ushort* vp = VT + vbase + (size_t)srow * 2048 + soff;
        uint4 va = *(const uint4*)vp, vb = *(const uint4*)(vp + 32);
        *(uint4*)&Ks[0][0][srow * KVS + soff] = ka;
        *(uint4*)&Ks[0][1][srow * KVS + soff] = kb2;
        *(uint4*)&Vs[0][0][srow * KVS + soff] = va;
        *(uint4*)&Vs[0][1][srow * KVS + soff] = vb;
    }

    for (int i = 0; i < 32; i++) {
        const int p = i & 1;
        __syncthreads();   // buf p staged + old readers of buf p^1 done

        // issue next-tile loads immediately (consumed at iter end)
        uint4 ka, kb2, va, vb;
        if (i < 31) {
            int j0 = (i + 1) * 64;
            const ushort* kp = Kb + base + (size_t)(j0 + srow) * 1024 + soff;
            ka = *(const uint4*)kp; kb2 = *(const uint4*)(kp + 32);
            const ushort* vp = VT + vbase + (size_t)srow * 2048 + j0 + soff;
            va = *(const uint4*)vp; vb = *(const uint4*)(vp + 32);
        }

        // S = Q K^T
        bf16x8 bk0[4], bk1[4];
#pragma unroll
        for (int nt = 0; nt < 4; nt++) {
            bk0[nt] = *(const bf16x8*)&Ks[p][0][(nt * 16 + l16) * KVS + quad * 8];
            bk1[nt] = *(const bf16x8*)&Ks[p][1][(nt * 16 + l16) * KVS + quad * 8];
        }
        f32x4 sacc[2][4] = {};
#pragma unroll
        for (int rt = 0; rt < 2; rt++)
#pragma unroll
            for (int nt = 0; nt < 4; nt++) {
                sacc[rt][nt] = __builtin_amdgcn_mfma_f32_16x16x32_bf16(
                    aq[rt][0], bk0[nt], sacc[rt][nt], 0, 0, 0);
                sacc[rt][nt] = __builtin_amdgcn_mfma_f32_16x16x32_bf16(
                    aq[rt][1], bk1[nt], sacc[rt][nt], 0, 0, 0);
            }

        // p = 2^s via raw v_exp_f32 (log2e pre-folded into q); fp32 lsum;
        // P truncated to bf16 for the PV MFMA
#pragma unroll
        for (int rt = 0; rt < 2; rt++)
#pragma unroll
            for (int nt = 0; nt < 4; nt++)
#pragma unroll
                for (int r = 0; r < 4; r++) {
                    float pv = __builtin_amdgcn_exp2f(sacc[rt][nt][r]);
                    lsum[rt][r] += pv;
                    Ps[wave][nt >> 1][(rt * 16 + quad * 4 + r) * KVS + (nt & 1) * 16 + l16]
                        = (ushort)(__float_as_uint(pv) >> 16);
                }

        // O += P V (wave-private Ps: in-wave DS ordering, no barrier)
        bf16x8 bv0[4], bv1[4], ap[2][2];
#pragma unroll
        for (int ht = 0; ht < 4; ht++) {
            bv0[ht] = *(const bf16x8*)&Vs[p][0][(ht * 16 + l16) * KVS + quad * 8];
            bv1[ht] = *(const bf16x8*)&Vs[p][1][(ht * 16 + l16) * KVS + quad * 8];
        }
#pragma unroll
        for (int rt = 0; rt < 2; rt++) {
            ap[rt][0] = *(const bf16x8*)&Ps[wave][0][(rt * 16 + l16) * KVS + quad * 8];
            ap[rt][1] = *(const bf16x8*)&Ps[wave][1][(rt * 16 + l16) * KVS + quad * 8];
        }
#pragma unroll
        for (int rt = 0; rt < 2; rt++)
#pragma unroll
            for (int ht = 0; ht < 4; ht++) {
                o[rt][ht] = __builtin_amdgcn_mfma_f32_16x16x32_bf16(
                    ap[rt][0], bv0[ht], o[rt][ht], 0, 0, 0);
                o[rt][ht] = __builtin_amdgcn_mfma_f32_16x16x32_bf16(
                    ap[rt][1], bv1[ht], o[rt][ht], 0, 0, 0);
            }

        // stage next tile into buf p^1
        if (i < 31) {
            *(uint4*)&Ks[p ^ 1][0][srow * KVS + soff] = ka;
            *(uint4*)&Ks[p ^ 1][1][srow * KVS + soff] = kb2;
            *(uint4*)&Vs[p ^ 1][0][srow * KVS + soff] = va;
            *(uint4*)&Vs[p ^ 1][1][srow * KVS + soff] = vb;
        }
    }

    // reduce row sums over the quad's 16 lanes; normalize; write ctx
#pragma unroll
    for (int rt = 0; rt < 2; rt++)
#pragma unroll
        for (int r = 0; r < 4; r++) {
            float t = lsum[rt][r];
#pragma unroll
            for (int d = 1; d < 16; d <<= 1) t += __shfl_xor(t, d, 64);
            float inv = 1.f / t;
            int row = q0 + wq + rt * 16 + quad * 4 + r;
#pragma unroll
            for (int ht = 0; ht < 4; ht++)
                CTX[base + (size_t)row * 1024 + ht * 16 + l16] = f2bf(o[rt][ht][r] * inv);
        }
}

// ---------------------------------------------------------------------------
extern "C" void kernel_launch(void* const* d_in, const int* in_sizes, int n_in,
                              void* d_out, int out_size, void* d_ws, size_t ws_size,
                              hipStream_t stream)
{
    (void)in_sizes; (void)n_in; (void)out_size; (void)ws_size;
    const float* x  = (const float*)d_in[0];
    const float* Wq = (const float*)d_in[1];
    const float* bq = (const float*)d_in[2];
    const float* Wk = (const float*)d_in[3];
    const float* bk = (const float*)d_in[4];
    const float* Wv = (const float*)d_in[5];
    const float* bv = (const float*)d_in[6];
    const float* Wo = (const float*)d_in[7];
    const float* bo = (const float*)d_in[8];

    char* ws = (char*)d_ws;
    const size_t MT = (size_t)4096 * 1024 * 2;   // 8 MB per [4096][1024] bf16
    ushort* q  = (ushort*)(ws + 0 * MT);         // q, later ctx (alias-safe)
    ushort* k  = (ushort*)(ws + 1 * MT);
    ushort* v  = (ushort*)(ws + 2 * MT);         // vT[(b*16+h)*64+hd][t]
    ushort* WT = (ushort*)(ws + 3 * MT);         // 4 x 1M bf16 (q,k,v,o stacked)
    ushort* xb = (ushort*)d_out;                 // scratch in out (dead before gemm_out)

    conv<<<dim3(4096), 256, 0, stream>>>(x, Wq, Wk, Wv, Wo, xb, WT);

    gemm_qkv<<<dim3(24, 32), 256, 0, stream>>>(xb, WT, bq, bk, bv, q, k, v);

    attn<<<dim3(512), 256, 0, stream>>>(q, k, v, q /*ctx aliases q*/);

    gemm_out<<<dim3(16, 32), 256, 0, stream>>>(q, WT + 3 * 1048576, bo, (float*)d_out);
}